// Round 1
// baseline (441.916 us; speedup 1.0000x reference)
//
#include <hip/hip_runtime.h>
#include <hip/hip_bf16.h>
#include <stdint.h>

#define B_ROWS 32768
#define DIM    1024
#define KACT   102       // int(1024*0.1)
#define KPAD   104

typedef short bf16x8 __attribute__((ext_vector_type(8)));
typedef float f32x4  __attribute__((ext_vector_type(4)));

__device__ __forceinline__ unsigned short f2bf(float f) {
  union { float f; unsigned u; } v; v.f = f;
  unsigned u = v.u;
  unsigned r = u + 0x7fffu + ((u >> 16) & 1u);   // RNE
  return (unsigned short)(r >> 16);
}

// async global->LDS, 16B per lane
#define GLDS(g, l) __builtin_amdgcn_global_load_lds( \
    (__attribute__((address_space(1))) void*)(g),    \
    (__attribute__((address_space(3))) void*)(l), 16, 0, 0)

// ---------------------------------------------------------------------------
// K1: x fp32 -> bf16 (ws), plus per-column sum(|x|) into fp64 accumulators.
// grid 1024 blocks x 256 thr; block handles 32 rows; thread owns cols 4t..4t+3.
// ---------------------------------------------------------------------------
__global__ __launch_bounds__(256) void k_conv_colsum(
    const float* __restrict__ x, unsigned short* __restrict__ xb,
    double* __restrict__ colsum) {
  const int t  = threadIdx.x;
  const int c0 = t * 4;
  const size_t base = (size_t)blockIdx.x * 32 * DIM;
  double s0 = 0.0, s1 = 0.0, s2 = 0.0, s3 = 0.0;
  #pragma unroll 4
  for (int j = 0; j < 32; ++j) {
    size_t off = base + (size_t)j * DIM + c0;
    float4 v = *(const float4*)(x + off);
    s0 += fabsf(v.x); s1 += fabsf(v.y); s2 += fabsf(v.z); s3 += fabsf(v.w);
    ushort4 o;
    o.x = f2bf(v.x); o.y = f2bf(v.y); o.z = f2bf(v.z); o.w = f2bf(v.w);
    *(ushort4*)(xb + off) = o;
  }
  unsafeAtomicAdd(&colsum[c0 + 0], s0);
  unsafeAtomicAdd(&colsum[c0 + 1], s1);
  unsafeAtomicAdd(&colsum[c0 + 2], s2);
  unsafeAtomicAdd(&colsum[c0 + 3], s3);
}

// ---------------------------------------------------------------------------
// K2: w1 [K][N] fp32 -> w1t [N][K] bf16 (transpose+convert). grid 256 x 256.
// ---------------------------------------------------------------------------
__global__ __launch_bounds__(256) void k_w1t(const float* __restrict__ w1,
                                             unsigned short* __restrict__ w1t) {
  __shared__ unsigned short tile[64][65];
  const int t  = threadIdx.x;
  const int bx = blockIdx.x & 15;   // col tile of w1
  const int by = blockIdx.x >> 4;   // row tile of w1
  for (int e = t; e < 64 * 64; e += 256) {
    int r = e >> 6, c = e & 63;
    tile[r][c] = f2bf(w1[(size_t)(by * 64 + r) * DIM + bx * 64 + c]);
  }
  __syncthreads();
  for (int e = t; e < 64 * 64; e += 256) {
    int c = e >> 6, r = e & 63;
    w1t[(size_t)(bx * 64 + c) * DIM + by * 64 + r] = tile[r][c];
  }
}

// ---------------------------------------------------------------------------
// K3: top-102 by column sum (rank method, tie-break lower index = lax.top_k).
// 1 block x 1024 threads. Emits compacted active list + col->slot map.
// ---------------------------------------------------------------------------
__global__ __launch_bounds__(1024) void k_topk(const double* __restrict__ colsum,
                                               int* __restrict__ act,
                                               int* __restrict__ cmap) {
  __shared__ double sv[DIM];
  __shared__ int    af[DIM];
  const int d = threadIdx.x;
  sv[d] = colsum[d];
  __syncthreads();
  const double sd = sv[d];
  int rank = 0;
  for (int j = 0; j < DIM; ++j) {
    double s = sv[j];
    rank += (s > sd || (s == sd && j < d)) ? 1 : 0;
  }
  const int isact = rank < KACT;
  af[d] = isact;
  __syncthreads();
  int pos = 0;
  for (int j = 0; j < d; ++j) pos += af[j];
  cmap[d] = isact ? pos : -1;
  if (isact) act[pos] = d;
}

// ---------------------------------------------------------------------------
// K4: gather compact W2sub/W3sub [KPAD][KPAD] fp32 (pad rows/cols zeroed).
// grid KPAD blocks x 128 threads.
// ---------------------------------------------------------------------------
__global__ __launch_bounds__(128) void k_wsub(const float* __restrict__ w2,
                                              const float* __restrict__ w3,
                                              const int* __restrict__ act,
                                              float* __restrict__ W2sub,
                                              float* __restrict__ W3sub) {
  const int i = blockIdx.x;
  const int j = threadIdx.x;
  if (j >= KPAD) return;
  float v2 = 0.f, v3 = 0.f;
  if (i < KACT && j < KACT) {
    size_t o = (size_t)act[i] * DIM + act[j];
    v2 = w2[o]; v3 = w3[o];
  }
  W2sub[i * KPAD + j] = v2;
  W3sub[i * KPAD + j] = v3;
}

// ---------------------------------------------------------------------------
// K5: r1 = x @ w1 in bf16 MFMA. 128x128 tile, BK=32, 4 waves (2x2), m97-style
// double-buffered global_load_lds staging with XOR chunk swizzle so the
// 16B fragment ds_reads are bank-conflict-free.
// A = xb [M][K] bf16, Bt = w1t [N][K] bf16, C fp32 [M][N].
// grid = (M/128)*(N/128) = 2048, 256 threads.
// ---------------------------------------------------------------------------
__global__ __launch_bounds__(256) void k_gemm_r1(const unsigned short* __restrict__ A,
                                                 const unsigned short* __restrict__ Bt,
                                                 float* __restrict__ C) {
  constexpr int K  = DIM;
  constexpr int NT = K / 32;
  __shared__ unsigned short As[2][128 * 32];
  __shared__ unsigned short Bs[2][128 * 32];
  const int t    = threadIdx.x;
  const int lane = t & 63;
  const int wave = t >> 6;
  const int wrow = wave >> 1;
  const int wcol = wave & 1;
  const int brow = blockIdx.x >> 3;   // M/128 = 256 row tiles
  const int bcol = blockIdx.x & 7;    // N/128 = 8 col tiles

  const unsigned short* Ab0 = A  + (size_t)brow * 128 * K;
  const unsigned short* Bb0 = Bt + (size_t)bcol * 128 * K;

  // staging: LDS chunk p (16B each) holds global chunk (r = p>>2, c = (p&3)^swz(r))
  const int p0 = t, p1 = t + 256;
  const int r0 = p0 >> 2, c0 = (p0 & 3) ^ ((r0 >> 1) & 3);
  const int r1 = p1 >> 2, c1 = (p1 & 3) ^ ((r1 >> 1) & 3);
  const size_t so0 = (size_t)r0 * K + c0 * 8;
  const size_t so1 = (size_t)r1 * K + c1 * 8;

  // fragment read positions (shorts): chunk = R*4 + (kg ^ ((R>>1)&3))
  const int kg = lane >> 4;
  const int la = lane & 15;
  int posA[4], posB[4];
  #pragma unroll
  for (int i = 0; i < 4; ++i) {
    int R = wrow * 64 + i * 16 + la;
    posA[i] = (R * 4 + (kg ^ ((R >> 1) & 3))) * 8;
    int Cc = wcol * 64 + i * 16 + la;
    posB[i] = (Cc * 4 + (kg ^ ((Cc >> 1) & 3))) * 8;
  }

  f32x4 acc[4][4];
  #pragma unroll
  for (int mi = 0; mi < 4; ++mi)
    #pragma unroll
    for (int ni = 0; ni < 4; ++ni)
      acc[mi][ni] = (f32x4){0.f, 0.f, 0.f, 0.f};

  auto stage = [&](int kt, int buf) {
    const int k0 = kt * 32;
    GLDS(Ab0 + so0 + k0, &As[buf][p0 * 8]);
    GLDS(Ab0 + so1 + k0, &As[buf][p1 * 8]);
    GLDS(Bb0 + so0 + k0, &Bs[buf][p0 * 8]);
    GLDS(Bb0 + so1 + k0, &Bs[buf][p1 * 8]);
  };

  stage(0, 0);
  #pragma unroll 2
  for (int kt = 0; kt < NT; ++kt) {
    __syncthreads();                       // drains stage(kt) (vmcnt before barrier)
    const int cur = kt & 1;
    if (kt + 1 < NT) stage(kt + 1, cur ^ 1);
    bf16x8 av[4], bv[4];
    #pragma unroll
    for (int i = 0; i < 4; ++i) av[i] = *(const bf16x8*)(&As[cur][posA[i]]);
    #pragma unroll
    for (int i = 0; i < 4; ++i) bv[i] = *(const bf16x8*)(&Bs[cur][posB[i]]);
    #pragma unroll
    for (int mi = 0; mi < 4; ++mi)
      #pragma unroll
      for (int ni = 0; ni < 4; ++ni)
        acc[mi][ni] = __builtin_amdgcn_mfma_f32_16x16x32_bf16(av[mi], bv[ni],
                                                              acc[mi][ni], 0, 0, 0);
  }

  // epilogue: C/D layout col = lane&15, row = (lane>>4)*4 + reg
  const int orow = brow * 128 + wrow * 64 + (lane >> 4) * 4;
  const int ocol = bcol * 128 + wcol * 64 + la;
  #pragma unroll
  for (int mi = 0; mi < 4; ++mi)
    #pragma unroll
    for (int ni = 0; ni < 4; ++ni)
      #pragma unroll
      for (int r = 0; r < 4; ++r)
        C[(size_t)(orow + mi * 16 + r) * DIM + ocol + ni * 16] = acc[mi][ni][r];
}

// ---------------------------------------------------------------------------
// K6: r2/r3. Block = 256 thr, 64 rows. W subs staged in LDS; per 16-row chunk:
// gather active x cols -> LDS, fp32 dot-102 (8 rows/thread register block),
// gate, stage results in LDS, write dense fp32 rows (zeros elsewhere).
// grid 512.
// ---------------------------------------------------------------------------
__global__ __launch_bounds__(256) void k_r23(const float* __restrict__ x,
                                             const float* __restrict__ W2sub,
                                             const float* __restrict__ W3sub,
                                             const int* __restrict__ act,
                                             const int* __restrict__ cmap,
                                             float* __restrict__ out2,
                                             float* __restrict__ out3) {
  __shared__ float W2s[KPAD * KPAD];
  __shared__ float W3s[KPAD * KPAD];
  __shared__ float xs [16 * KPAD];
  __shared__ float r2s[16 * KPAD];
  __shared__ float r3s[16 * KPAD];
  __shared__ int   cms[DIM];
  __shared__ int   acs[KACT];
  const int t    = threadIdx.x;
  const int row0 = blockIdx.x * 64;

  for (int e = t; e < KPAD * KPAD; e += 256) { W2s[e] = W2sub[e]; W3s[e] = W3sub[e]; }
  for (int e = t; e < DIM; e += 256) cms[e] = cmap[e];
  if (t < KACT) acs[t] = act[t];
  __syncthreads();

  const int  j   = t & 127;
  const int  rg  = t >> 7;
  const bool jok = j < KACT;

  for (int ch = 0; ch < 4; ++ch) {
    const int r0 = row0 + ch * 16;
    // phase A: gather x at active columns (pad cols zeroed)
    for (int e = t; e < 16 * KPAD; e += 256) {
      int r = e / KPAD, i = e - r * KPAD;
      xs[e] = (i < KACT) ? x[(size_t)(r0 + r) * DIM + acs[i]] : 0.0f;
    }
    __syncthreads();
    // phase B: two K=102 dots per output, 8 rows per thread
    if (jok) {
      float a2[8], a3[8];
      #pragma unroll
      for (int r = 0; r < 8; ++r) { a2[r] = 0.f; a3[r] = 0.f; }
      for (int i = 0; i < KPAD; i += 4) {
        float w2v[4], w3v[4];
        #pragma unroll
        for (int q = 0; q < 4; ++q) {
          w2v[q] = W2s[(i + q) * KPAD + j];
          w3v[q] = W3s[(i + q) * KPAD + j];
        }
        #pragma unroll
        for (int r = 0; r < 8; ++r) {
          f32x4 xv = *(const f32x4*)(&xs[(rg * 8 + r) * KPAD + i]);
          a2[r] += xv[0] * w2v[0] + xv[1] * w2v[1] + xv[2] * w2v[2] + xv[3] * w2v[3];
          a3[r] += xv[0] * w3v[0] + xv[1] * w3v[1] + xv[2] * w3v[2] + xv[3] * w3v[3];
        }
      }
      #pragma unroll
      for (int r = 0; r < 8; ++r) {
        int rr = rg * 8 + r;
        float g = xs[rr * KPAD + j];
        r2s[rr * KPAD + j] = a2[r] * g;
        r3s[rr * KPAD + j] = a3[r] * a3[r] * g;
      }
    }
    __syncthreads();
    // phase C: dense fp32 row writes (float4), zeros at inactive columns
    {
      const int c0 = t * 4;
      const int4 cm = *(const int4*)(&cms[c0]);
      #pragma unroll 4
      for (int r = 0; r < 16; ++r) {
        const float* rr2 = &r2s[r * KPAD];
        const float* rr3 = &r3s[r * KPAD];
        float4 o2, o3;
        o2.x = (cm.x >= 0) ? rr2[cm.x] : 0.f;  o3.x = (cm.x >= 0) ? rr3[cm.x] : 0.f;
        o2.y = (cm.y >= 0) ? rr2[cm.y] : 0.f;  o3.y = (cm.y >= 0) ? rr3[cm.y] : 0.f;
        o2.z = (cm.z >= 0) ? rr2[cm.z] : 0.f;  o3.z = (cm.z >= 0) ? rr3[cm.z] : 0.f;
        o2.w = (cm.w >= 0) ? rr2[cm.w] : 0.f;  o3.w = (cm.w >= 0) ? rr3[cm.w] : 0.f;
        size_t oo = (size_t)(r0 + r) * DIM + c0;
        *(float4*)(out2 + oo) = o2;
        *(float4*)(out3 + oo) = o3;
      }
    }
    __syncthreads();
  }
}

// ---------------------------------------------------------------------------
extern "C" void kernel_launch(void* const* d_in, const int* in_sizes, int n_in,
                              void* d_out, int out_size, void* d_ws, size_t ws_size,
                              hipStream_t stream) {
  const float* x  = (const float*)d_in[0];
  const float* w1 = (const float*)d_in[1];
  const float* w2 = (const float*)d_in[2];
  const float* w3 = (const float*)d_in[3];

  float* out1 = (float*)d_out;
  float* out2 = out1 + (size_t)B_ROWS * DIM;
  float* out3 = out2 + (size_t)B_ROWS * DIM;

  char* ws = (char*)d_ws;
  unsigned short* xb   = (unsigned short*)ws;                    // 67108864 B
  unsigned short* w1t  = (unsigned short*)(ws + 67108864);       //  2097152 B
  double*         csum = (double*)(ws + 69206016);               //     8192 B
  int*            act  = (int*)(ws + 69214208);                  //      512 B
  int*            cmap = (int*)(ws + 69214720);                  //     4096 B
  float*          W2sub= (float*)(ws + 69218816);                //    43264 B
  float*          W3sub= (float*)(ws + 69262080);                //    43264 B

  hipMemsetAsync(csum, 0, DIM * sizeof(double), stream);
  k_conv_colsum<<<dim3(1024), dim3(256), 0, stream>>>(x, xb, csum);
  k_w1t        <<<dim3(256),  dim3(256), 0, stream>>>(w1, w1t);
  k_topk       <<<dim3(1),    dim3(1024),0, stream>>>(csum, act, cmap);
  k_wsub       <<<dim3(KPAD), dim3(128), 0, stream>>>(w2, w3, act, W2sub, W3sub);
  k_gemm_r1    <<<dim3(2048), dim3(256), 0, stream>>>(xb, w1t, out1);
  k_r23        <<<dim3(512),  dim3(256), 0, stream>>>(x, W2sub, W3sub, act, cmap, out2, out3);
}

// Round 2
// 283.941 us; speedup vs baseline: 1.5564x; 1.5564x over previous
//
#include <hip/hip_runtime.h>
#include <hip/hip_bf16.h>
#include <stdint.h>

#define B_ROWS 32768
#define DIM    1024
#define KACT   102       // int(1024*0.1)
#define KPAD   104

typedef short bf16x8 __attribute__((ext_vector_type(8)));
typedef float f32x4  __attribute__((ext_vector_type(4)));

__device__ __forceinline__ unsigned short f2bf(float f) {
  union { float f; unsigned u; } v; v.f = f;
  unsigned u = v.u;
  unsigned r = u + 0x7fffu + ((u >> 16) & 1u);   // RNE
  return (unsigned short)(r >> 16);
}

// async global->LDS, 16B per lane
#define GLDS(g, l) __builtin_amdgcn_global_load_lds( \
    (__attribute__((address_space(1))) void*)(g),    \
    (__attribute__((address_space(3))) void*)(l), 16, 0, 0)

// ---------------------------------------------------------------------------
// K1: x fp32 -> bf16 (ws), plus per-column partial sum(|x|) (f32, per block).
// 512 blocks x 256 thr; block = 64 rows; thread owns cols 4t..4t+3.
// No atomics: partial[block][col] written coalesced.
// ---------------------------------------------------------------------------
__global__ __launch_bounds__(256) void k_conv(
    const float* __restrict__ x, unsigned short* __restrict__ xb,
    float* __restrict__ partial) {
  const int t  = threadIdx.x;
  const int c0 = t * 4;
  const size_t base = (size_t)blockIdx.x * 64 * DIM;
  float s0 = 0.f, s1 = 0.f, s2 = 0.f, s3 = 0.f;
  #pragma unroll 4
  for (int j = 0; j < 64; ++j) {
    size_t off = base + (size_t)j * DIM + c0;
    float4 v = *(const float4*)(x + off);
    s0 += fabsf(v.x); s1 += fabsf(v.y); s2 += fabsf(v.z); s3 += fabsf(v.w);
    ushort4 o;
    o.x = f2bf(v.x); o.y = f2bf(v.y); o.z = f2bf(v.z); o.w = f2bf(v.w);
    *(ushort4*)(xb + off) = o;
  }
  float4 p; p.x = s0; p.y = s1; p.z = s2; p.w = s3;
  *(float4*)(partial + (size_t)blockIdx.x * DIM + c0) = p;
}

// ---------------------------------------------------------------------------
// K2: w1 [K][N] fp32 -> w1t [N][K] bf16 (transpose+convert). grid 256 x 256.
// ---------------------------------------------------------------------------
__global__ __launch_bounds__(256) void k_w1t(const float* __restrict__ w1,
                                             unsigned short* __restrict__ w1t) {
  __shared__ unsigned short tile[64][65];
  const int t  = threadIdx.x;
  const int bx = blockIdx.x & 15;   // col tile of w1
  const int by = blockIdx.x >> 4;   // row tile of w1
  for (int e = t; e < 64 * 64; e += 256) {
    int r = e >> 6, c = e & 63;
    tile[r][c] = f2bf(w1[(size_t)(by * 64 + r) * DIM + bx * 64 + c]);
  }
  __syncthreads();
  for (int e = t; e < 64 * 64; e += 256) {
    int c = e >> 6, r = e & 63;
    w1t[(size_t)(bx * 64 + c) * DIM + by * 64 + r] = tile[r][c];
  }
}

// ---------------------------------------------------------------------------
// K3a: reduce 512 partials -> 8 k-slice partials (f32), deterministic.
// grid 64 (8 colgroups x 8 kslices) x 128 thr.
// ---------------------------------------------------------------------------
__global__ __launch_bounds__(128) void k_reduce1(const float* __restrict__ partial,
                                                 float* __restrict__ p2) {
  const int c  = (blockIdx.x & 7) * 128 + threadIdx.x;
  const int ks = blockIdx.x >> 3;
  float s = 0.f;
  #pragma unroll 8
  for (int p = ks * 64; p < ks * 64 + 64; ++p) s += partial[(size_t)p * DIM + c];
  p2[ks * DIM + c] = s;
}

// ---------------------------------------------------------------------------
// K3b: finalize colsums in f64 (8 slices), rank each column vs all 1024
// (tie-break lower index == lax.top_k). grid 4 x 256, flags out.
// ---------------------------------------------------------------------------
__global__ __launch_bounds__(256) void k_rank(const float* __restrict__ p2,
                                              int* __restrict__ flags) {
  __shared__ double sv[DIM];
  const int t = threadIdx.x;
  for (int e = t; e < DIM; e += 256) {
    double s = 0.0;
    #pragma unroll
    for (int ks = 0; ks < 8; ++ks) s += (double)p2[ks * DIM + e];
    sv[e] = s;
  }
  __syncthreads();
  const int d = blockIdx.x * 256 + t;
  const double sd = sv[d];
  int rank = 0;
  for (int j = 0; j < DIM; ++j) {
    double s = sv[j];
    rank += (s > sd || (s == sd && j < d)) ? 1 : 0;
  }
  flags[d] = (rank < KACT) ? 1 : 0;
}

// ---------------------------------------------------------------------------
// K3c: compact via ballot-scan. 1 block x 1024 threads.
// ---------------------------------------------------------------------------
__global__ __launch_bounds__(1024) void k_compact(const int* __restrict__ flags,
                                                  int* __restrict__ act,
                                                  int* __restrict__ cmap) {
  __shared__ int wcnt[16];
  const int d = threadIdx.x;
  const int f = flags[d];
  unsigned long long m = __ballot(f != 0);
  const int lane = d & 63, w = d >> 6;
  if (lane == 0) wcnt[w] = __popcll(m);
  __syncthreads();
  int off = 0;
  for (int i = 0; i < w; ++i) off += wcnt[i];
  int pos = off + __popcll(m & ((1ull << lane) - 1ull));
  cmap[d] = f ? pos : -1;
  if (f) act[pos] = d;
}

// ---------------------------------------------------------------------------
// K4: gather compact W2sub/W3sub [KPAD][KPAD] fp32 (pad rows/cols zeroed).
// ---------------------------------------------------------------------------
__global__ __launch_bounds__(128) void k_wsub(const float* __restrict__ w2,
                                              const float* __restrict__ w3,
                                              const int* __restrict__ act,
                                              float* __restrict__ W2sub,
                                              float* __restrict__ W3sub) {
  const int i = blockIdx.x;
  const int j = threadIdx.x;
  if (j >= KPAD) return;
  float v2 = 0.f, v3 = 0.f;
  if (i < KACT && j < KACT) {
    size_t o = (size_t)act[i] * DIM + act[j];
    v2 = w2[o]; v3 = w3[o];
  }
  W2sub[i * KPAD + j] = v2;
  W3sub[i * KPAD + j] = v3;
}

// ---------------------------------------------------------------------------
// K5: r1 = x @ w1 bf16 MFMA, 128x128 tile, BK=32, m97 structure +
// XCD-aware bijective swizzle (nwg=2048 divisible by 8).
// ---------------------------------------------------------------------------
__global__ __launch_bounds__(256) void k_gemm_r1(const unsigned short* __restrict__ A,
                                                 const unsigned short* __restrict__ Bt,
                                                 float* __restrict__ C) {
  constexpr int K  = DIM;
  constexpr int NT = K / 32;
  __shared__ unsigned short As[2][128 * 32];
  __shared__ unsigned short Bs[2][128 * 32];
  const int t    = threadIdx.x;
  const int lane = t & 63;
  const int wave = t >> 6;
  const int wrow = wave >> 1;
  const int wcol = wave & 1;
  // XCD swizzle: each XCD gets 256 contiguous (brow-major) tiles -> A-panel
  // reuse (x8) stays in the XCD-local L2; B (2MB) L2-resident everywhere.
  const int swz  = (blockIdx.x & 7) * 256 + (blockIdx.x >> 3);
  const int brow = swz >> 3;   // 256 row tiles
  const int bcol = swz & 7;    // 8 col tiles

  const unsigned short* Ab0 = A  + (size_t)brow * 128 * K;
  const unsigned short* Bb0 = Bt + (size_t)bcol * 128 * K;

  // staging: LDS chunk p (16B) holds global chunk (r = p>>2, c = (p&3)^swz(r))
  const int p0 = t, p1 = t + 256;
  const int r0 = p0 >> 2, c0 = (p0 & 3) ^ ((r0 >> 1) & 3);
  const int r1 = p1 >> 2, c1 = (p1 & 3) ^ ((r1 >> 1) & 3);
  const size_t so0 = (size_t)r0 * K + c0 * 8;
  const size_t so1 = (size_t)r1 * K + c1 * 8;

  const int kg = lane >> 4;
  const int la = lane & 15;
  int posA[4], posB[4];
  #pragma unroll
  for (int i = 0; i < 4; ++i) {
    int R = wrow * 64 + i * 16 + la;
    posA[i] = (R * 4 + (kg ^ ((R >> 1) & 3))) * 8;
    int Cc = wcol * 64 + i * 16 + la;
    posB[i] = (Cc * 4 + (kg ^ ((Cc >> 1) & 3))) * 8;
  }

  f32x4 acc[4][4];
  #pragma unroll
  for (int mi = 0; mi < 4; ++mi)
    #pragma unroll
    for (int ni = 0; ni < 4; ++ni)
      acc[mi][ni] = (f32x4){0.f, 0.f, 0.f, 0.f};

  auto stage = [&](int kt, int buf) {
    const int k0 = kt * 32;
    GLDS(Ab0 + so0 + k0, &As[buf][p0 * 8]);
    GLDS(Ab0 + so1 + k0, &As[buf][p1 * 8]);
    GLDS(Bb0 + so0 + k0, &Bs[buf][p0 * 8]);
    GLDS(Bb0 + so1 + k0, &Bs[buf][p1 * 8]);
  };

  stage(0, 0);
  #pragma unroll 2
  for (int kt = 0; kt < NT; ++kt) {
    __syncthreads();                       // drains stage(kt)
    const int cur = kt & 1;
    if (kt + 1 < NT) stage(kt + 1, cur ^ 1);
    bf16x8 av[4], bv[4];
    #pragma unroll
    for (int i = 0; i < 4; ++i) av[i] = *(const bf16x8*)(&As[cur][posA[i]]);
    #pragma unroll
    for (int i = 0; i < 4; ++i) bv[i] = *(const bf16x8*)(&Bs[cur][posB[i]]);
    #pragma unroll
    for (int mi = 0; mi < 4; ++mi)
      #pragma unroll
      for (int ni = 0; ni < 4; ++ni)
        acc[mi][ni] = __builtin_amdgcn_mfma_f32_16x16x32_bf16(av[mi], bv[ni],
                                                              acc[mi][ni], 0, 0, 0);
  }

  // C/D layout: col = lane&15, row = (lane>>4)*4 + reg
  const int orow = brow * 128 + wrow * 64 + (lane >> 4) * 4;
  const int ocol = bcol * 128 + wcol * 64 + la;
  #pragma unroll
  for (int mi = 0; mi < 4; ++mi)
    #pragma unroll
    for (int ni = 0; ni < 4; ++ni)
      #pragma unroll
      for (int r = 0; r < 4; ++r)
        C[(size_t)(orow + mi * 16 + r) * DIM + ocol + ni * 16] = acc[mi][ni][r];
}

// ---------------------------------------------------------------------------
// K6: r2/r3. 256 blocks x 512 thr, 128 rows/block in 8 chunks of 16 rows.
// Dense coalesced x reads compacted into LDS via cmap (no scattered global
// gather); double-buffered xs with issue-early / write-late staging so HBM
// read latency hides under compute + output writes.
// ---------------------------------------------------------------------------
__global__ __launch_bounds__(512) void k_r23(const float* __restrict__ x,
                                             const float* __restrict__ W2sub,
                                             const float* __restrict__ W3sub,
                                             const int* __restrict__ cmap,
                                             float* __restrict__ out2,
                                             float* __restrict__ out3) {
  __shared__ float W2s[KPAD * KPAD];
  __shared__ float W3s[KPAD * KPAD];
  __shared__ float xs[2][16 * KPAD];
  __shared__ float r2s[16 * KPAD];
  __shared__ float r3s[16 * KPAD];
  __shared__ int   cms[DIM];
  const int t    = threadIdx.x;
  const int row0 = blockIdx.x * 128;

  for (int e = t; e < KPAD * KPAD; e += 512) { W2s[e] = W2sub[e]; W3s[e] = W3sub[e]; }
  for (int e = t; e < DIM; e += 512) cms[e] = cmap[e];
  for (int e = t; e < 2 * 16 * KPAD; e += 512) ((float*)xs)[e] = 0.f;  // incl pads
  __syncthreads();

  const int  j   = t & 127;
  const int  rg  = (t >> 7) & 3;      // 4 row-groups of 4 rows
  const bool jok = j < KACT;

  // dense coalesced load of one 16-row chunk into 8 f32x4 regs
  auto LOADR = [&](int ch, f32x4* ld) {
    const size_t base = (size_t)(row0 + ch * 16) * DIM;
    #pragma unroll
    for (int it = 0; it < 8; ++it) {
      int e = t + it * 512;
      int r = e >> 8, c4 = e & 255;
      ld[it] = *(const f32x4*)(x + base + (size_t)r * DIM + c4 * 4);
    }
  };
  // compact regs into xs[buf] via cmap (inactive cols dropped)
  auto XSW = [&](int buf, const f32x4* ld) {
    #pragma unroll
    for (int it = 0; it < 8; ++it) {
      int e = t + it * 512;
      int r = e >> 8, c4 = e & 255;
      #pragma unroll
      for (int q = 0; q < 4; ++q) {
        int m = cms[c4 * 4 + q];
        if (m >= 0) xs[buf][r * KPAD + m] = ld[it][q];
      }
    }
  };
  auto COMPUTE = [&](int buf) {
    if (jok) {
      float a2[4], a3[4];
      #pragma unroll
      for (int r = 0; r < 4; ++r) { a2[r] = 0.f; a3[r] = 0.f; }
      for (int i = 0; i < KPAD; i += 4) {
        float w2v[4], w3v[4];
        #pragma unroll
        for (int q = 0; q < 4; ++q) {
          w2v[q] = W2s[(i + q) * KPAD + j];
          w3v[q] = W3s[(i + q) * KPAD + j];
        }
        #pragma unroll
        for (int r = 0; r < 4; ++r) {
          f32x4 xv = *(const f32x4*)(&xs[buf][(rg * 4 + r) * KPAD + i]);
          a2[r] += xv[0] * w2v[0] + xv[1] * w2v[1] + xv[2] * w2v[2] + xv[3] * w2v[3];
          a3[r] += xv[0] * w3v[0] + xv[1] * w3v[1] + xv[2] * w3v[2] + xv[3] * w3v[3];
        }
      }
      #pragma unroll
      for (int r = 0; r < 4; ++r) {
        int rr = rg * 4 + r;
        float g = xs[buf][rr * KPAD + j];
        r2s[rr * KPAD + j] = a2[r] * g;
        r3s[rr * KPAD + j] = a3[r] * a3[r] * g;
      }
    }
  };
  auto WRITEOUT = [&](int ch) {
    const int r0 = row0 + ch * 16;
    const int c0 = (t & 255) * 4;
    const int rh = t >> 8;              // 0 or 1
    const int4 cm = *(const int4*)(&cms[c0]);
    #pragma unroll
    for (int k = 0; k < 8; ++k) {
      int r = rh + k * 2;
      const float* rr2 = &r2s[r * KPAD];
      const float* rr3 = &r3s[r * KPAD];
      float4 o2, o3;
      o2.x = (cm.x >= 0) ? rr2[cm.x] : 0.f;  o3.x = (cm.x >= 0) ? rr3[cm.x] : 0.f;
      o2.y = (cm.y >= 0) ? rr2[cm.y] : 0.f;  o3.y = (cm.y >= 0) ? rr3[cm.y] : 0.f;
      o2.z = (cm.z >= 0) ? rr2[cm.z] : 0.f;  o3.z = (cm.z >= 0) ? rr3[cm.z] : 0.f;
      o2.w = (cm.w >= 0) ? rr2[cm.w] : 0.f;  o3.w = (cm.w >= 0) ? rr3[cm.w] : 0.f;
      size_t oo = (size_t)(r0 + r) * DIM + c0;
      *(float4*)(out2 + oo) = o2;
      *(float4*)(out3 + oo) = o3;
    }
  };

  f32x4 ldA[8], ldB[8];                 // static names (no runtime reg indexing)
  LOADR(0, ldA);
  XSW(0, ldA);
  __syncthreads();
  for (int ch2 = 0; ch2 < 8; ch2 += 2) {
    // even chunk: compute xs[0], prefetch ch2+1 into ldB
    if (ch2 + 1 < 8) LOADR(ch2 + 1, ldB);
    COMPUTE(0);
    __syncthreads();
    WRITEOUT(ch2);
    if (ch2 + 1 < 8) XSW(1, ldB);
    __syncthreads();
    // odd chunk: compute xs[1], prefetch ch2+2 into ldA
    if (ch2 + 2 < 8) LOADR(ch2 + 2, ldA);
    COMPUTE(1);
    __syncthreads();
    WRITEOUT(ch2 + 1);
    if (ch2 + 2 < 8) XSW(0, ldA);
    __syncthreads();
  }
}

// ---------------------------------------------------------------------------
extern "C" void kernel_launch(void* const* d_in, const int* in_sizes, int n_in,
                              void* d_out, int out_size, void* d_ws, size_t ws_size,
                              hipStream_t stream) {
  const float* x  = (const float*)d_in[0];
  const float* w1 = (const float*)d_in[1];
  const float* w2 = (const float*)d_in[2];
  const float* w3 = (const float*)d_in[3];

  float* out1 = (float*)d_out;
  float* out2 = out1 + (size_t)B_ROWS * DIM;
  float* out3 = out2 + (size_t)B_ROWS * DIM;

  char* ws = (char*)d_ws;
  unsigned short* xb     = (unsigned short*)ws;                  // 67108864 B
  unsigned short* w1t    = (unsigned short*)(ws + 67108864);     //  2097152 B
  float*          partial= (float*)(ws + 69206016);              //  2097152 B
  float*          p2     = (float*)(ws + 71303168);              //    32768 B
  int*            flags  = (int*)(ws + 71335936);                //     4096 B
  int*            act    = (int*)(ws + 71340032);                //      512 B
  int*            cmap   = (int*)(ws + 71340544);                //     4096 B
  float*          W2sub  = (float*)(ws + 71344640);              //    43264 B
  float*          W3sub  = (float*)(ws + 71387904);              //    43264 B

  k_conv    <<<dim3(512),  dim3(256),  0, stream>>>(x, xb, partial);
  k_w1t     <<<dim3(256),  dim3(256),  0, stream>>>(w1, w1t);
  k_reduce1 <<<dim3(64),   dim3(128),  0, stream>>>(partial, p2);
  k_rank    <<<dim3(4),    dim3(256),  0, stream>>>(p2, flags);
  k_compact <<<dim3(1),    dim3(1024), 0, stream>>>(flags, act, cmap);
  k_wsub    <<<dim3(KPAD), dim3(128),  0, stream>>>(w2, w3, act, W2sub, W3sub);
  k_gemm_r1 <<<dim3(2048), dim3(256),  0, stream>>>(xb, w1t, out1);
  k_r23     <<<dim3(256),  dim3(512),  0, stream>>>(x, W2sub, W3sub, cmap, out2, out3);
}

// Round 3
// 256.849 us; speedup vs baseline: 1.7205x; 1.1055x over previous
//
#include <hip/hip_runtime.h>
#include <hip/hip_bf16.h>
#include <stdint.h>

#define B_ROWS 32768
#define DIM    1024
#define KACT   102       // int(1024*0.1)
#define KPAD   104

typedef short bf16x8 __attribute__((ext_vector_type(8)));
typedef float f32x4  __attribute__((ext_vector_type(4)));

__device__ __forceinline__ unsigned short f2bf(float f) {
  union { float f; unsigned u; } v; v.f = f;
  unsigned u = v.u;
  unsigned r = u + 0x7fffu + ((u >> 16) & 1u);   // RNE
  return (unsigned short)(r >> 16);
}

// async global->LDS, 16B per lane
#define GLDS(g, l) __builtin_amdgcn_global_load_lds( \
    (__attribute__((address_space(1))) void*)(g),    \
    (__attribute__((address_space(3))) void*)(l), 16, 0, 0)

// ---------------------------------------------------------------------------
// K1: x fp32 -> bf16 (ws), plus per-column partial sum(|x|) (f32, per block).
// ---------------------------------------------------------------------------
__global__ __launch_bounds__(256) void k_conv(
    const float* __restrict__ x, unsigned short* __restrict__ xb,
    float* __restrict__ partial) {
  const int t  = threadIdx.x;
  const int c0 = t * 4;
  const size_t base = (size_t)blockIdx.x * 64 * DIM;
  float s0 = 0.f, s1 = 0.f, s2 = 0.f, s3 = 0.f;
  #pragma unroll 4
  for (int j = 0; j < 64; ++j) {
    size_t off = base + (size_t)j * DIM + c0;
    float4 v = *(const float4*)(x + off);
    s0 += fabsf(v.x); s1 += fabsf(v.y); s2 += fabsf(v.z); s3 += fabsf(v.w);
    ushort4 o;
    o.x = f2bf(v.x); o.y = f2bf(v.y); o.z = f2bf(v.z); o.w = f2bf(v.w);
    *(ushort4*)(xb + off) = o;
  }
  float4 p; p.x = s0; p.y = s1; p.z = s2; p.w = s3;
  *(float4*)(partial + (size_t)blockIdx.x * DIM + c0) = p;
}

// ---------------------------------------------------------------------------
// K2: w1 [K][N] fp32 -> w1t [N][K] bf16 (transpose+convert).
// ---------------------------------------------------------------------------
__global__ __launch_bounds__(256) void k_w1t(const float* __restrict__ w1,
                                             unsigned short* __restrict__ w1t) {
  __shared__ unsigned short tile[64][65];
  const int t  = threadIdx.x;
  const int bx = blockIdx.x & 15;
  const int by = blockIdx.x >> 4;
  for (int e = t; e < 64 * 64; e += 256) {
    int r = e >> 6, c = e & 63;
    tile[r][c] = f2bf(w1[(size_t)(by * 64 + r) * DIM + bx * 64 + c]);
  }
  __syncthreads();
  for (int e = t; e < 64 * 64; e += 256) {
    int c = e >> 6, r = e & 63;
    w1t[(size_t)(bx * 64 + c) * DIM + by * 64 + r] = tile[r][c];
  }
}

// ---------------------------------------------------------------------------
// K3a: reduce 512 partials -> 8 k-slice partials (deterministic).
// ---------------------------------------------------------------------------
__global__ __launch_bounds__(128) void k_reduce1(const float* __restrict__ partial,
                                                 float* __restrict__ p2) {
  const int c  = (blockIdx.x & 7) * 128 + threadIdx.x;
  const int ks = blockIdx.x >> 3;
  float s = 0.f;
  #pragma unroll 8
  for (int p = ks * 64; p < ks * 64 + 64; ++p) s += partial[(size_t)p * DIM + c];
  p2[ks * DIM + c] = s;
}

// ---------------------------------------------------------------------------
// K3b: finalize colsums in f64, rank (tie-break lower index == lax.top_k).
// ---------------------------------------------------------------------------
__global__ __launch_bounds__(256) void k_rank(const float* __restrict__ p2,
                                              int* __restrict__ flags) {
  __shared__ double sv[DIM];
  const int t = threadIdx.x;
  for (int e = t; e < DIM; e += 256) {
    double s = 0.0;
    #pragma unroll
    for (int ks = 0; ks < 8; ++ks) s += (double)p2[ks * DIM + e];
    sv[e] = s;
  }
  __syncthreads();
  const int d = blockIdx.x * 256 + t;
  const double sd = sv[d];
  int rank = 0;
  for (int j = 0; j < DIM; ++j) {
    double s = sv[j];
    rank += (s > sd || (s == sd && j < d)) ? 1 : 0;
  }
  flags[d] = (rank < KACT) ? 1 : 0;
}

// ---------------------------------------------------------------------------
// K3c: compact via ballot-scan. 1 block x 1024 threads.
// ---------------------------------------------------------------------------
__global__ __launch_bounds__(1024) void k_compact(const int* __restrict__ flags,
                                                  int* __restrict__ act,
                                                  int* __restrict__ cmap) {
  __shared__ int wcnt[16];
  const int d = threadIdx.x;
  const int f = flags[d];
  unsigned long long m = __ballot(f != 0);
  const int lane = d & 63, w = d >> 6;
  if (lane == 0) wcnt[w] = __popcll(m);
  __syncthreads();
  int off = 0;
  for (int i = 0; i < w; ++i) off += wcnt[i];
  int pos = off + __popcll(m & ((1ull << lane) - 1ull));
  cmap[d] = f ? pos : -1;
  if (f) act[pos] = d;
}

// ---------------------------------------------------------------------------
// K4: gather compact W2sub/W3sub [KPAD][KPAD] fp32.
// ---------------------------------------------------------------------------
__global__ __launch_bounds__(128) void k_wsub(const float* __restrict__ w2,
                                              const float* __restrict__ w3,
                                              const int* __restrict__ act,
                                              float* __restrict__ W2sub,
                                              float* __restrict__ W3sub) {
  const int i = blockIdx.x;
  const int j = threadIdx.x;
  if (j >= KPAD) return;
  float v2 = 0.f, v3 = 0.f;
  if (i < KACT && j < KACT) {
    size_t o = (size_t)act[i] * DIM + act[j];
    v2 = w2[o]; v3 = w3[o];
  }
  W2sub[i * KPAD + j] = v2;
  W3sub[i * KPAD + j] = v3;
}

// ---------------------------------------------------------------------------
// K5: r1 = x @ w1 bf16 MFMA. 256x256 tile, 8 waves (2x4), BK=32, 4-slot LDS
// ring, counted-vmcnt pipeline (stage kt+2 while computing kt), setprio
// around MFMA clusters, raw s_barrier pairs per phase, XOR bank swizzle
// (chunk ^= (chunk>>3)&3) applied on pre-swizzled global source + ds_read.
// A = xb [M][K], Bt = w1t [N][K], C fp32 [M][N]. grid 512 x 512 thr.
// ---------------------------------------------------------------------------
#define VMW4 asm volatile("s_waitcnt vmcnt(4)" ::: "memory")
#define VMW0 asm volatile("s_waitcnt vmcnt(0)" ::: "memory")
#define NOP_ (void)0

#define STAGE_A(KT) do { \
  GLDS(Abase + (size_t)sr0 * 1024 + (KT) * 32 + sc0 * 8, &Asl[((KT)&3)*8192 + p0*8]); \
  GLDS(Abase + (size_t)sr1 * 1024 + (KT) * 32 + sc1 * 8, &Asl[((KT)&3)*8192 + p1*8]); \
} while (0)
#define STAGE_B(KT) do { \
  GLDS(Bbase + (size_t)sr0 * 1024 + (KT) * 32 + sc0 * 8, &Bsl[((KT)&3)*8192 + p0*8]); \
  GLDS(Bbase + (size_t)sr1 * 1024 + (KT) * 32 + sc1 * 8, &Bsl[((KT)&3)*8192 + p1*8]); \
} while (0)

#define PH0(SLOT, STAGE_STMT) do { \
  _Pragma("unroll") for (int i = 0; i < 4; ++i) \
    areg[i] = *(const bf16x8*)(&Asl[(SLOT)*8192 + aoff0 + i * 512]); \
  _Pragma("unroll") for (int i = 0; i < 4; ++i) \
    breg[i] = *(const bf16x8*)(&Bsl[(SLOT)*8192 + boff0 + i * 512]); \
  STAGE_STMT; \
  __builtin_amdgcn_s_barrier(); \
  __builtin_amdgcn_s_setprio(1); \
  _Pragma("unroll") for (int mi = 0; mi < 4; ++mi) \
  _Pragma("unroll") for (int ni = 0; ni < 4; ++ni) \
    acc[mi][ni] = __builtin_amdgcn_mfma_f32_16x16x32_bf16(areg[mi], breg[ni], acc[mi][ni], 0, 0, 0); \
  __builtin_amdgcn_s_setprio(0); \
  __builtin_amdgcn_s_barrier(); \
} while (0)

#define PH1(SLOT, STAGE_STMT, WAIT_STMT) do { \
  _Pragma("unroll") for (int i = 0; i < 4; ++i) \
    areg[i] = *(const bf16x8*)(&Asl[(SLOT)*8192 + aoff0 + 2048 + i * 512]); \
  STAGE_STMT; \
  WAIT_STMT; \
  __builtin_amdgcn_s_barrier(); \
  __builtin_amdgcn_s_setprio(1); \
  _Pragma("unroll") for (int mi = 0; mi < 4; ++mi) \
  _Pragma("unroll") for (int ni = 0; ni < 4; ++ni) \
    acc[4 + mi][ni] = __builtin_amdgcn_mfma_f32_16x16x32_bf16(areg[mi], breg[ni], acc[4 + mi][ni], 0, 0, 0); \
  __builtin_amdgcn_s_setprio(0); \
  __builtin_amdgcn_s_barrier(); \
} while (0)

__global__ __launch_bounds__(512, 1) void k_gemm_r1(
    const unsigned short* __restrict__ A,
    const unsigned short* __restrict__ Bt,
    float* __restrict__ C) {
  __shared__ unsigned short Asl[4 * 8192];   // 4 slots x [256 rows][32 k] bf16
  __shared__ unsigned short Bsl[4 * 8192];

  const int t    = threadIdx.x;
  const int lane = t & 63;
  const int wave = t >> 6;
  const int wm   = wave >> 2;       // 0..1  (m-half of tile, 128 rows)
  const int wn   = wave & 3;        // 0..3  (64-col strip)
  const int la   = lane & 15;
  const int kg   = lane >> 4;
  const int kgx  = kg ^ ((la >> 1) & 3);   // physical k-chunk after swizzle

  // XCD-bijective swizzle: 512 blocks, 64 contiguous per XCD
  const int swz  = (blockIdx.x & 7) * 64 + (blockIdx.x >> 3);
  const int brow = swz >> 2;        // 0..127
  const int bcol = swz & 3;         // 0..3

  const unsigned short* Abase = A  + (size_t)brow * 256 * 1024;
  const unsigned short* Bbase = Bt + (size_t)bcol * 256 * 1024;

  // staging: physical chunk p holds logical chunk q = p ^ ((p>>3)&3)
  const int p0 = t, p1 = t + 512;
  const int q0 = p0 ^ ((p0 >> 3) & 3);
  const int q1 = p1 ^ ((p1 >> 3) & 3);
  const int sr0 = q0 >> 2, sc0 = q0 & 3;
  const int sr1 = q1 >> 2, sc1 = q1 & 3;

  // fragment read offsets (elements within slot): row*32 + kgx*8
  const int aoff0 = (wm * 128 + la) * 32 + kgx * 8;   // + mt*512 (+2048 for mh=1)
  const int boff0 = (wn * 64  + la) * 32 + kgx * 8;   // + nt*512

  f32x4 acc[8][4];
  #pragma unroll
  for (int mi = 0; mi < 8; ++mi)
    #pragma unroll
    for (int ni = 0; ni < 4; ++ni)
      acc[mi][ni] = (f32x4){0.f, 0.f, 0.f, 0.f};

  bf16x8 areg[4], breg[4];

  // prologue: KT0, KT1 staged; wait leaves KT1's 4 loads in flight
  STAGE_A(0); STAGE_B(0); STAGE_A(1); STAGE_B(1);
  VMW4;
  __builtin_amdgcn_s_barrier();

  // steady: compute kt, stage kt+2, one counted wait per K-tile
  for (int kt4 = 0; kt4 < 28; kt4 += 4) {
    PH0(0, STAGE_A(kt4 + 2)); PH1(0, STAGE_B(kt4 + 2), VMW4);
    PH0(1, STAGE_A(kt4 + 3)); PH1(1, STAGE_B(kt4 + 3), VMW4);
    PH0(2, STAGE_A(kt4 + 4)); PH1(2, STAGE_B(kt4 + 4), VMW4);
    PH0(3, STAGE_A(kt4 + 5)); PH1(3, STAGE_B(kt4 + 5), VMW4);
  }
  PH0(0, STAGE_A(30)); PH1(0, STAGE_B(30), VMW4);   // kt=28
  PH0(1, STAGE_A(31)); PH1(1, STAGE_B(31), VMW4);   // kt=29
  PH0(2, NOP_);        PH1(2, NOP_, VMW0);          // kt=30 (final drain)
  PH0(3, NOP_);        PH1(3, NOP_, NOP_);          // kt=31

  // epilogue: C/D layout col = lane&15, row = (lane>>4)*4 + reg
  const int orow0 = brow * 256 + wm * 128 + (lane >> 4) * 4;
  const int ocol0 = bcol * 256 + wn * 64 + la;
  #pragma unroll
  for (int mi = 0; mi < 8; ++mi)
    #pragma unroll
    for (int ni = 0; ni < 4; ++ni)
      #pragma unroll
      for (int r = 0; r < 4; ++r)
        C[(size_t)(orow0 + mi * 16 + r) * DIM + ocol0 + ni * 16] = acc[mi][ni][r];
}

// ---------------------------------------------------------------------------
// K6: r2/r3. 256 blocks x 512 thr, 128 rows/block in 8 chunks of 16 rows.
// ---------------------------------------------------------------------------
__global__ __launch_bounds__(512) void k_r23(const float* __restrict__ x,
                                             const float* __restrict__ W2sub,
                                             const float* __restrict__ W3sub,
                                             const int* __restrict__ cmap,
                                             float* __restrict__ out2,
                                             float* __restrict__ out3) {
  __shared__ float W2s[KPAD * KPAD];
  __shared__ float W3s[KPAD * KPAD];
  __shared__ float xs[2][16 * KPAD];
  __shared__ float r2s[16 * KPAD];
  __shared__ float r3s[16 * KPAD];
  __shared__ int   cms[DIM];
  const int t    = threadIdx.x;
  const int row0 = blockIdx.x * 128;

  for (int e = t; e < KPAD * KPAD; e += 512) { W2s[e] = W2sub[e]; W3s[e] = W3sub[e]; }
  for (int e = t; e < DIM; e += 512) cms[e] = cmap[e];
  for (int e = t; e < 2 * 16 * KPAD; e += 512) ((float*)xs)[e] = 0.f;
  __syncthreads();

  const int  j   = t & 127;
  const int  rg  = (t >> 7) & 3;
  const bool jok = j < KACT;

  auto LOADR = [&](int ch, f32x4* ld) {
    const size_t base = (size_t)(row0 + ch * 16) * DIM;
    #pragma unroll
    for (int it = 0; it < 8; ++it) {
      int e = t + it * 512;
      int r = e >> 8, c4 = e & 255;
      ld[it] = *(const f32x4*)(x + base + (size_t)r * DIM + c4 * 4);
    }
  };
  auto XSW = [&](int buf, const f32x4* ld) {
    #pragma unroll
    for (int it = 0; it < 8; ++it) {
      int e = t + it * 512;
      int r = e >> 8, c4 = e & 255;
      #pragma unroll
      for (int q = 0; q < 4; ++q) {
        int m = cms[c4 * 4 + q];
        if (m >= 0) xs[buf][r * KPAD + m] = ld[it][q];
      }
    }
  };
  auto COMPUTE = [&](int buf) {
    if (jok) {
      float a2[4], a3[4];
      #pragma unroll
      for (int r = 0; r < 4; ++r) { a2[r] = 0.f; a3[r] = 0.f; }
      for (int i = 0; i < KPAD; i += 4) {
        float w2v[4], w3v[4];
        #pragma unroll
        for (int q = 0; q < 4; ++q) {
          w2v[q] = W2s[(i + q) * KPAD + j];
          w3v[q] = W3s[(i + q) * KPAD + j];
        }
        #pragma unroll
        for (int r = 0; r < 4; ++r) {
          f32x4 xv = *(const f32x4*)(&xs[buf][(rg * 4 + r) * KPAD + i]);
          a2[r] += xv[0] * w2v[0] + xv[1] * w2v[1] + xv[2] * w2v[2] + xv[3] * w2v[3];
          a3[r] += xv[0] * w3v[0] + xv[1] * w3v[1] + xv[2] * w3v[2] + xv[3] * w3v[3];
        }
      }
      #pragma unroll
      for (int r = 0; r < 4; ++r) {
        int rr = rg * 4 + r;
        float g = xs[buf][rr * KPAD + j];
        r2s[rr * KPAD + j] = a2[r] * g;
        r3s[rr * KPAD + j] = a3[r] * a3[r] * g;
      }
    }
  };
  auto WRITEOUT = [&](int ch) {
    const int r0 = row0 + ch * 16;
    const int c0 = (t & 255) * 4;
    const int rh = t >> 8;
    const int4 cm = *(const int4*)(&cms[c0]);
    #pragma unroll
    for (int k = 0; k < 8; ++k) {
      int r = rh + k * 2;
      const float* rr2 = &r2s[r * KPAD];
      const float* rr3 = &r3s[r * KPAD];
      float4 o2, o3;
      o2.x = (cm.x >= 0) ? rr2[cm.x] : 0.f;  o3.x = (cm.x >= 0) ? rr3[cm.x] : 0.f;
      o2.y = (cm.y >= 0) ? rr2[cm.y] : 0.f;  o3.y = (cm.y >= 0) ? rr3[cm.y] : 0.f;
      o2.z = (cm.z >= 0) ? rr2[cm.z] : 0.f;  o3.z = (cm.z >= 0) ? rr3[cm.z] : 0.f;
      o2.w = (cm.w >= 0) ? rr2[cm.w] : 0.f;  o3.w = (cm.w >= 0) ? rr3[cm.w] : 0.f;
      size_t oo = (size_t)(r0 + r) * DIM + c0;
      *(float4*)(out2 + oo) = o2;
      *(float4*)(out3 + oo) = o3;
    }
  };

  f32x4 ldA[8], ldB[8];
  LOADR(0, ldA);
  XSW(0, ldA);
  __syncthreads();
  for (int ch2 = 0; ch2 < 8; ch2 += 2) {
    if (ch2 + 1 < 8) LOADR(ch2 + 1, ldB);
    COMPUTE(0);
    __syncthreads();
    WRITEOUT(ch2);
    if (ch2 + 1 < 8) XSW(1, ldB);
    __syncthreads();
    if (ch2 + 2 < 8) LOADR(ch2 + 2, ldA);
    COMPUTE(1);
    __syncthreads();
    WRITEOUT(ch2 + 1);
    if (ch2 + 2 < 8) XSW(0, ldA);
    __syncthreads();
  }
}

// ---------------------------------------------------------------------------
extern "C" void kernel_launch(void* const* d_in, const int* in_sizes, int n_in,
                              void* d_out, int out_size, void* d_ws, size_t ws_size,
                              hipStream_t stream) {
  const float* x  = (const float*)d_in[0];
  const float* w1 = (const float*)d_in[1];
  const float* w2 = (const float*)d_in[2];
  const float* w3 = (const float*)d_in[3];

  float* out1 = (float*)d_out;
  float* out2 = out1 + (size_t)B_ROWS * DIM;
  float* out3 = out2 + (size_t)B_ROWS * DIM;

  char* ws = (char*)d_ws;
  unsigned short* xb     = (unsigned short*)ws;                  // 67108864 B
  unsigned short* w1t    = (unsigned short*)(ws + 67108864);     //  2097152 B
  float*          partial= (float*)(ws + 69206016);              //  2097152 B
  float*          p2     = (float*)(ws + 71303168);              //    32768 B
  int*            flags  = (int*)(ws + 71335936);                //     4096 B
  int*            act    = (int*)(ws + 71340032);                //      512 B
  int*            cmap   = (int*)(ws + 71340544);                //     4096 B
  float*          W2sub  = (float*)(ws + 71344640);              //    43264 B
  float*          W3sub  = (float*)(ws + 71387904);              //    43264 B

  k_conv    <<<dim3(512),  dim3(256),  0, stream>>>(x, xb, partial);
  k_w1t     <<<dim3(256),  dim3(256),  0, stream>>>(w1, w1t);
  k_reduce1 <<<dim3(64),   dim3(128),  0, stream>>>(partial, p2);
  k_rank    <<<dim3(4),    dim3(256),  0, stream>>>(p2, flags);
  k_compact <<<dim3(1),    dim3(1024), 0, stream>>>(flags, act, cmap);
  k_wsub    <<<dim3(KPAD), dim3(128),  0, stream>>>(w2, w3, act, W2sub, W3sub);
  k_gemm_r1 <<<dim3(512),  dim3(512),  0, stream>>>(xb, w1t, out1);
  k_r23     <<<dim3(256),  dim3(512),  0, stream>>>(x, W2sub, W3sub, cmap, out2, out3);
}